// Round 8
// baseline (696.106 us; speedup 1.0000x reference)
//
#include <hip/hip_runtime.h>
#include <cstdint>
#include <cstddef>

#define B_   8
#define N_   2048
#define D_   1024
#define DK_  256
#define M_   (B_ * N_)   // 16384
#define TOPK 32

typedef unsigned short ushort_t;
typedef float  fvec4 __attribute__((ext_vector_type(4)));
typedef short  bvec8 __attribute__((ext_vector_type(8)));   // 8 bf16 (bits)
typedef float  avec4 __attribute__((ext_vector_type(4)));   // f32 MFMA acc
typedef double dvec2 __attribute__((ext_vector_type(2)));
typedef int    ivec4 __attribute__((ext_vector_type(4)));   // 16B staging

__device__ inline ushort_t f32_to_bf16_rn(float f) {
  unsigned u = __float_as_uint(f);
  u += 0x7fffu + ((u >> 16) & 1u);     // RNE (no inf/nan in this data)
  return (ushort_t)(u >> 16);
}

// --------------------------------------------------------------------------
// Kernel 1: fused Q/K projection GEMM, f64 accumulation on the VALU.
// Tile 128(m) x 128(j), BK=16, 8x8/thread. LDS holds f64 (cvt at staging:
// 16 cvt/tile vs 256 in-loop). Fragment remap for conflict-free reads:
//   A-fragment rows ty*8+i  -> 16-lane broadcast (free)
//   B-fragment cols tx+16*jj -> 8B lane stride, all 32 banks (free)
// Stage writes are 4-8 way conflicted but only 12 instrs/tile (reads: 192).
// --------------------------------------------------------------------------
__global__ __launch_bounds__(256) void proj_kernel(
    const float* __restrict__ X, const float* __restrict__ Wq,
    const float* __restrict__ bq, const float* __restrict__ Wk,
    const float* __restrict__ bk, double* __restrict__ Qd,
    double* __restrict__ Kd, ushort_t* __restrict__ Qbf,
    ushort_t* __restrict__ Kbf)
{
  __shared__ double As[16][130];   // [k][m], 1040B rows (16B-aligned)
  __shared__ double Bs[16][136];   // [k][j], 1088B rows (16B-aligned)
  const int tid = threadIdx.x;
  const int tx = tid & 15;         // owns B-cols tx + 16*jj
  const int ty = tid >> 4;         // owns A-rows ty*8 + i
  const int m0 = blockIdx.y * 128;
  const int j0 = blockIdx.x * 128;          // 0,128,256,384
  const bool isQ = (j0 < 256);
  const float* Wp = isQ ? Wq : Wk;
  const float* bp = isQ ? bq : bk;
  const int jw = isQ ? j0 : (j0 - 256);

  const int ar = tid >> 1;            // 0..127 (A row)
  const int ac8 = (tid & 1) * 8;      // 0 or 8 (A k-group)
  const int bkk = tid >> 4;           // 0..15 (B k)
  const int bj8 = (tid & 15) * 8;     // 0..120 (B j-group)

  double acc[8][8];
#pragma unroll
  for (int i = 0; i < 8; i++)
#pragma unroll
    for (int j = 0; j < 8; j++) acc[i][j] = 0.0;

  for (int k0 = 0; k0 < D_; k0 += 16) {
    {  // A tile: 128 rows x 16 k -> As[k][m] (f64). 8 cvt + 8 ds_write_b64.
      const fvec4 v0 = *(const fvec4*)&X[(size_t)(m0 + ar) * D_ + k0 + ac8];
      const fvec4 v1 = *(const fvec4*)&X[(size_t)(m0 + ar) * D_ + k0 + ac8 + 4];
#pragma unroll
      for (int c = 0; c < 4; c++) {
        As[ac8 + c][ar]     = (double)v0[c];
        As[ac8 + c + 4][ar] = (double)v1[c];
      }
    }
    {  // B tile: 16 k x 128 j -> Bs[k][j] (f64). 8 cvt + 4 ds_write_b128.
      const fvec4 w0 = *(const fvec4*)&Wp[(size_t)(k0 + bkk) * DK_ + jw + bj8];
      const fvec4 w1 = *(const fvec4*)&Wp[(size_t)(k0 + bkk) * DK_ + jw + bj8 + 4];
#pragma unroll
      for (int c = 0; c < 4; c++) {
        Bs[bkk][bj8 + c]     = (double)w0[c];
        Bs[bkk][bj8 + c + 4] = (double)w1[c];
      }
    }
    __syncthreads();
#pragma unroll
    for (int kk = 0; kk < 16; kk++) {
      double a[8], b[8];
      const dvec2 a01 = *(const dvec2*)&As[kk][ty * 8];
      const dvec2 a23 = *(const dvec2*)&As[kk][ty * 8 + 2];
      const dvec2 a45 = *(const dvec2*)&As[kk][ty * 8 + 4];
      const dvec2 a67 = *(const dvec2*)&As[kk][ty * 8 + 6];
      a[0] = a01[0]; a[1] = a01[1]; a[2] = a23[0]; a[3] = a23[1];
      a[4] = a45[0]; a[5] = a45[1]; a[6] = a67[0]; a[7] = a67[1];
#pragma unroll
      for (int jj = 0; jj < 8; jj++) b[jj] = Bs[kk][tx + 16 * jj];
#pragma unroll
      for (int i = 0; i < 8; i++)
#pragma unroll
        for (int jj = 0; jj < 8; jj++)
          acc[i][jj] = fma(a[i], b[jj], acc[i][jj]);
    }
    __syncthreads();
  }

#pragma unroll
  for (int i = 0; i < 8; i++) {
    const int m = m0 + ty * 8 + i;
#pragma unroll
    for (int jj = 0; jj < 8; jj++) {
      const int c = jw + tx + 16 * jj;       // lane-consecutive -> coalesced
      const double v = acc[i][jj] + (double)bp[c];
      const size_t off = (size_t)m * DK_ + c;
      if (isQ) {
        Qd[off] = v;
        if (Qbf) Qbf[off] = f32_to_bf16_rn((float)v);
      } else {
        Kd[off] = v;
        if (Kbf) Kbf[off] = f32_to_bf16_rn((float)v);
      }
    }
  }
}

// --------------------------------------------------------------------------
// Kernel 2a: scores via bf16 MFMA 16x16x32 (candidate precision only).
// Proven r2/r5/r7 kernel, unchanged.
// --------------------------------------------------------------------------
__global__ __launch_bounds__(256) void score_bf16_kernel(
    const ushort_t* __restrict__ Qb, const ushort_t* __restrict__ Kb,
    float* __restrict__ out)
{
  __shared__ ushort_t Asl[128 * 40];
  __shared__ ushort_t Bsl[128 * 40];
  const int tid = threadIdx.x;
  const int b  = blockIdx.z;
  const int q0 = blockIdx.y * 128;
  const int m0 = blockIdx.x * 128;
  const int w = tid >> 6, lane = tid & 63;
  const int wq = (w >> 1) * 64, wm = (w & 1) * 64;
  const int rsel = lane & 15, ksel = (lane >> 4) * 8;

  avec4 acc[4][4];
#pragma unroll
  for (int i = 0; i < 4; i++)
#pragma unroll
    for (int j = 0; j < 4; j++) acc[i][j] = (avec4)(0.f);

  for (int k0 = 0; k0 < DK_; k0 += 32) {
#pragma unroll
    for (int cc = 0; cc < 2; cc++) {
      const int c = tid + cc * 256;
      const int r = c >> 2, part = c & 3;
      const ivec4 va = *(const ivec4*)&Qb[((size_t)b * N_ + q0 + r) * DK_ + k0 + part * 8];
      const ivec4 vb = *(const ivec4*)&Kb[((size_t)b * N_ + m0 + r) * DK_ + k0 + part * 8];
      *(ivec4*)&Asl[r * 40 + part * 8] = va;
      *(ivec4*)&Bsl[r * 40 + part * 8] = vb;
    }
    __syncthreads();
    bvec8 aF[4], bF[4];
#pragma unroll
    for (int mi = 0; mi < 4; mi++)
      aF[mi] = *(const bvec8*)&Asl[(wq + mi * 16 + rsel) * 40 + ksel];
#pragma unroll
    for (int nj = 0; nj < 4; nj++)
      bF[nj] = *(const bvec8*)&Bsl[(wm + nj * 16 + rsel) * 40 + ksel];
#pragma unroll
    for (int mi = 0; mi < 4; mi++)
#pragma unroll
      for (int nj = 0; nj < 4; nj++)
        acc[mi][nj] = __builtin_amdgcn_mfma_f32_16x16x32_bf16(
            aF[mi], bF[nj], acc[mi][nj], 0, 0, 0);
    __syncthreads();
  }

#pragma unroll
  for (int mi = 0; mi < 4; mi++)
#pragma unroll
    for (int nj = 0; nj < 4; nj++)
#pragma unroll
      for (int r = 0; r < 4; r++) {
        const int row = q0 + wq + mi * 16 + (lane >> 4) * 4 + r;
        const int col = m0 + wm + nj * 16 + (lane & 15);
        out[((size_t)b * N_ + row) * N_ + col] = acc[mi][nj][r] * 0.0625f;
      }
}

// --------------------------------------------------------------------------
// Kernel 2b (fallback if ws too small for bf16 copies): f32 scores from f64.
// --------------------------------------------------------------------------
__global__ __launch_bounds__(256) void score_f64_kernel(
    const double* __restrict__ Qd, const double* __restrict__ Kd,
    float* __restrict__ out)
{
  __shared__ float As[16][68];
  __shared__ float Bs[16][68];
  const int tid = threadIdx.x;
  const int tx = tid & 15, ty = tid >> 4;
  const int b  = blockIdx.z;
  const int q0 = blockIdx.y * 64;
  const int m0 = blockIdx.x * 64;
  const size_t rowbase = (size_t)b * N_;

  float acc[4][4];
#pragma unroll
  for (int i = 0; i < 4; i++)
#pragma unroll
    for (int j = 0; j < 4; j++) acc[i][j] = 0.f;

  for (int k0 = 0; k0 < DK_; k0 += 16) {
    const int mt = tid >> 4, kt = tid & 15;
#pragma unroll
    for (int p = 0; p < 4; p++) {
      const int m = mt + 16 * p;
      As[kt][m] = (float)Qd[(rowbase + q0 + m) * DK_ + k0 + kt];
      Bs[kt][m] = (float)Kd[(rowbase + m0 + m) * DK_ + k0 + kt];
    }
    __syncthreads();
#pragma unroll
    for (int kk = 0; kk < 16; kk++) {
      float a[4], bb[4];
#pragma unroll
      for (int i = 0; i < 4; i++) a[i] = As[kk][ty * 4 + i];
#pragma unroll
      for (int j = 0; j < 4; j++) bb[j] = Bs[kk][tx * 4 + j];
#pragma unroll
      for (int i = 0; i < 4; i++)
#pragma unroll
        for (int j = 0; j < 4; j++)
          acc[i][j] = fmaf(a[i], bb[j], acc[i][j]);
    }
    __syncthreads();
  }

#pragma unroll
  for (int i = 0; i < 4; i++) {
    const size_t r = (size_t)b * N_ + q0 + ty * 4 + i;
#pragma unroll
    for (int j = 0; j < 4; j++)
      out[r * N_ + m0 + tx * 4 + j] = acc[i][j] * 0.0625f;
  }
}

// --------------------------------------------------------------------------
// Kernel 3: per-row exact top-32 + softmax. One block (256 thr) per row.
// NEW: 2-pass radix on the top 16 bits (scores are bf16-grade; bucket floor
// + margin covers truncation) and wave-shuffle vmax/esum reductions.
// Selection still via f64 rescore (identical fma order) -> bit-compatible.
// --------------------------------------------------------------------------
__global__ __launch_bounds__(256) void topk_softmax_kernel(
    float* __restrict__ out, const double* __restrict__ Qd,
    const double* __restrict__ Kd, float margin)
{
  const int row = blockIdx.x;
  const int b   = row >> 11;
  const int tid = threadIdx.x;
  float* rowp = out + (size_t)row * N_;

  __shared__ float    s[N_];
  __shared__ double   qrow[DK_];
  __shared__ unsigned hist[256];
  __shared__ unsigned sfx[256];
  __shared__ int      cidx[128];
  __shared__ double   cval[128];
  __shared__ int      ncand_s;
  __shared__ unsigned prefix_s;
  __shared__ int      want_s;
  __shared__ double   wmax[4];
  __shared__ float    wsum[4];

  for (int i = tid; i < N_; i += 256) s[i] = rowp[i];
  qrow[tid] = Qd[(size_t)row * DK_ + tid];
  __syncthreads();

  // ---- 2-pass radix select on 16-bit keys (key = mono(f32) >> 16) ----
  unsigned prefix = 0;
  int want = TOPK;
  for (int pass = 0; pass < 2; pass++) {
    hist[tid] = 0;
    __syncthreads();
    const int shift_b = 8 - 8 * pass;
    for (int i = tid; i < N_; i += 256) {
      unsigned u = __float_as_uint(s[i]);
      u = (u & 0x80000000u) ? ~u : (u | 0x80000000u);
      const unsigned key = u >> 16;
      const bool ok = (pass == 0) || ((key >> 8) == prefix);
      if (ok) atomicAdd(&hist[(key >> shift_b) & 255u], 1u);
    }
    __syncthreads();
    sfx[tid] = hist[tid];
    __syncthreads();
    for (int st = 1; st < 256; st <<= 1) {
      const unsigned add = (tid + st < 256) ? sfx[tid + st] : 0u;
      __syncthreads();
      sfx[tid] += add;
      __syncthreads();
    }
    const int gt = (int)(sfx[tid] - hist[tid]);
    if (gt < want && (int)sfx[tid] >= want) {
      prefix_s = (prefix << 8) | (unsigned)tid;
      want_s = want - gt;
    }
    __syncthreads();
    prefix = prefix_s;
    want = want_s;
    __syncthreads();
  }
  // bucket floor value of the 16-bit key holding the 32nd-largest score
  const unsigned k16 = prefix;
  unsigned ulo;
  if (k16 & 0x8000u) ulo = (k16 << 16) ^ 0x80000000u;   // non-negative bucket
  else               ulo = ~((k16 << 16) | 0xFFFFu);    // negative bucket
  const float cthr = __uint_as_float(ulo) - margin;

  // ---- gather candidates ----
  if (tid == 0) ncand_s = 0;
  __syncthreads();
  for (int i = tid; i < N_; i += 256) {
    if (s[i] >= cthr) {
      const int p = atomicAdd(&ncand_s, 1);
      if (p < 128) cidx[p] = i;
    }
  }
  __syncthreads();
  int nc = ncand_s;
  if (nc > 128) nc = 128;

  // ---- f64 rescore (one wave per candidate; fma order == r5) ----
  const int wid = tid >> 6, lane = tid & 63;
  for (int base = 0; base < nc; base += 4) {
    const int c = base + wid;
    if (c < nc) {
      const double* kp = Kd + ((size_t)b * N_ + cidx[c]) * DK_;
      double a = 0.0;
#pragma unroll
      for (int q = 0; q < 4; q++)
        a = fma(qrow[lane * 4 + q], kp[lane * 4 + q], a);
#pragma unroll
      for (int off = 32; off > 0; off >>= 1) a += __shfl_xor(a, off);
      if (lane == 0) cval[c] = a * 0.0625;
    }
  }
  __syncthreads();

  // ---- exact top-32 among candidates (value desc, index asc) ----
  bool sel = false;
  double v = 0.0;
  int myidx = 0;
  if (tid < nc) {
    v = cval[tid];
    myidx = cidx[tid];
    int rank = 0;
    for (int j = 0; j < nc; j++) {
      const double vj = cval[j];
      rank += (vj > v) || (vj == v && cidx[j] < myidx);
    }
    sel = (rank < TOPK);
  }
  // parallel vmax
  double mv = (tid < nc) ? v : -1.0e300;
#pragma unroll
  for (int off = 32; off > 0; off >>= 1) {
    const double o = __shfl_xor(mv, off);
    mv = o > mv ? o : mv;
  }
  if (lane == 0) wmax[wid] = mv;
  __syncthreads();
  const double vmax = max(max(wmax[0], wmax[1]), max(wmax[2], wmax[3]));
  const float ev = sel ? expf((float)(v - vmax)) : 0.f;
  // parallel esum
  float es = ev;
#pragma unroll
  for (int off = 32; off > 0; off >>= 1) es += __shfl_xor(es, off);
  if (lane == 0) wsum[wid] = es;
  __syncthreads();
  const float esum = wsum[0] + wsum[1] + wsum[2] + wsum[3];

  // ---- write row: zeros + 32 softmax weights ----
  for (int i = tid; i < N_; i += 256) s[i] = 0.f;
  __syncthreads();
  if (sel) s[myidx] = ev / esum;
  __syncthreads();
  for (int i = tid; i < N_; i += 256) rowp[i] = s[i];
}

// --------------------------------------------------------------------------
extern "C" void kernel_launch(void* const* d_in, const int* in_sizes, int n_in,
                              void* d_out, int out_size, void* d_ws,
                              size_t ws_size, hipStream_t stream)
{
  const float* X  = (const float*)d_in[0];
  const float* Wq = (const float*)d_in[1];
  const float* bq = (const float*)d_in[2];
  const float* Wk = (const float*)d_in[3];
  const float* bk = (const float*)d_in[4];
  float* out = (float*)d_out;

  const size_t qk = (size_t)M_ * DK_;
  const size_t f64_bytes = qk * sizeof(double) * 2;           // 67.1 MB
  const size_t bf_bytes  = qk * sizeof(ushort_t) * 2;         // 16.8 MB
  if (ws_size < f64_bytes) return;
  const bool bfpath = (ws_size >= f64_bytes + bf_bytes);

  double* Qd = (double*)d_ws;
  double* Kd = Qd + qk;
  ushort_t* Qbf = (ushort_t*)(Kd + qk);
  ushort_t* Kbf = Qbf + qk;

  dim3 blk(256);
  proj_kernel<<<dim3(4, 128), blk, 0, stream>>>(
      X, Wq, bq, Wk, bk, Qd, Kd, bfpath ? Qbf : (ushort_t*)nullptr,
      bfpath ? Kbf : (ushort_t*)nullptr);

  float margin;
  if (bfpath) {
    score_bf16_kernel<<<dim3(N_ / 128, N_ / 128, B_), blk, 0, stream>>>(Qbf, Kbf, out);
    margin = 8e-3f;
  } else {
    score_f64_kernel<<<dim3(N_ / 64, N_ / 64, B_), blk, 0, stream>>>(Qd, Kd, out);
    margin = 2.5e-4f;
  }

  topk_softmax_kernel<<<dim3(M_), blk, 0, stream>>>(out, Qd, Kd, margin);
}